// Round 1
// 1491.019 us; speedup vs baseline: 1.2639x; 1.2639x over previous
//
#include <hip/hip_runtime.h>
#include <hip/hip_bf16.h>

// Problem: H=256, N=200000 sessions, U=20000 users.
// Runtime-detects whether float tensors are f32 or bf16, and whether
// user_ids is int64 or int32. Output dtype follows the float dtype.
#define HDIM 256
#define NROWS 200000
#define NUSERS 20000

// Harness-boilerplate symbol (defined, unused).
__global__ void UserSessionSimNet_21345987461278_kernel() {}

typedef __attribute__((ext_vector_type(8))) short bf16x8;  // 8 bf16 = 4 VGPRs
typedef __attribute__((ext_vector_type(4))) float f32x4;

__device__ __forceinline__ float b2f(__hip_bfloat16 v) { return __bfloat162float(v); }

// Dual-dtype load: f32m!=0 -> float buffer, else bf16 buffer.
__device__ __forceinline__ float ldx(const void* p, int idx, int f32m) {
  if (f32m != 0) return ((const float*)p)[idx];
  return b2f(((const __hip_bfloat16*)p)[idx]);
}

// round-to-nearest-even bf16 of x, returned as f32 bits with low 16 zeroed
__device__ __forceinline__ unsigned bfr(float x) {
  unsigned u = __float_as_uint(x);
  return (u + 0x7FFFu + ((u >> 16) & 1u)) & 0xFFFF0000u;
}

// split f32 -> bf16 hi + bf16 lo (hi+lo represents x to ~2^-16 relative)
__device__ __forceinline__ void split_store(float x, __hip_bfloat16* h, __hip_bfloat16* l) {
  unsigned hb = bfr(x);
  float rem = x - __uint_as_float(hb);
  unsigned lb = bfr(rem);
  *(unsigned short*)h = (unsigned short)(hb >> 16);
  *(unsigned short*)l = (unsigned short)(lb >> 16);
}

// flags[0]=uid-is-int32, flags[1]=bf16 vote count, flags[2]=f32 mode
// ---- init ------------------------------------------------------------------
__global__ void k_init(int* counts, int* cursor, float* denom, int* segmaxB, int* flags) {
  int i = blockIdx.x * 256 + threadIdx.x;
  if (i < 3) flags[i] = 0;
  if (i < NUSERS) {
    counts[i] = 0;
    cursor[i] = 0;
    denom[i] = 0.0f;
    segmaxB[i] = (int)0xFF800000;  // -inf
  }
}

// ---- float dtype vote: bits[14:7] of each 32-bit word -----------------------
__global__ void k_dtype(const unsigned int* words, int* flags) {
  int i = blockIdx.x * 256 + threadIdx.x;  // 0..1023
  unsigned int f = (words[i] >> 7) & 0xFFu;
  if (f >= 100u && f <= 140u) atomicAdd(&flags[1], 1);
}

__global__ void k_flagfin(int* flags) {
  if (threadIdx.x == 0 && blockIdx.x == 0) {
    flags[2] = (flags[1] < 512) ? 1 : 0;  // few exponent-like hits -> f32
  }
}

// ---- user_ids dtype detect + convert ---------------------------------------
__global__ void k_detect(const int* raw, int* flags) {
  int i = blockIdx.x * 256 + threadIdx.x;  // 0..1023
  if (raw[2 * i + 1] != 0) atomicOr(&flags[0], 1);
}

__global__ void k_cvt(const int* raw, const int* flags, int* uid32) {
  int i = blockIdx.x * 256 + threadIdx.x;
  if (i >= NROWS) return;
  if (flags[0] != 0) {
    uid32[i] = raw[i];      // int32 data
  } else {
    uid32[i] = raw[2 * i];  // int64 data: low word
  }
}

// ---- pack: M = Wq*Wk^T, P = Wv*W1a^T, W1b^T; all stored B^T-layout [n][k]
//      as bf16 hi/lo splits for MFMA consumption ------------------------------
__global__ void k_pack(const void* Wq, const void* Wk, const void* Wv, const void* W1,
                       const int* flags,
                       __hip_bfloat16* pMT_hi, __hip_bfloat16* pMT_lo,
                       __hip_bfloat16* pPT_hi, __hip_bfloat16* pPT_lo,
                       __hip_bfloat16* pBT_hi, __hip_bfloat16* pBT_lo) {
  int a = blockIdx.x;   // k index
  int j = threadIdx.x;  // n index
  int f32m = flags[2];
  float accM = 0.0f, accP = 0.0f;
  for (int c = 0; c < HDIM; ++c) {
    float wq = ldx(Wq, a * HDIM + c, f32m);
    float wv = ldx(Wv, a * HDIM + c, f32m);
    float wk = ldx(Wk, j * HDIM + c, f32m);
    float w1 = ldx(W1, j * 2 * HDIM + c, f32m);
    accM += wq * wk;
    accP += wv * w1;
  }
  // B^T layout: [n=j][k=a]
  split_store(accM, &pMT_hi[j * HDIM + a], &pMT_lo[j * HDIM + a]);
  split_store(accP, &pPT_hi[j * HDIM + a], &pPT_lo[j * HDIM + a]);
  float w1b = ldx(W1, j * 2 * HDIM + HDIM + a, f32m);  // (W1b^T)[k=a][n=j]
  split_store(w1b, &pBT_hi[j * HDIM + a], &pBT_lo[j * HDIM + a]);
}

// ---- CSR build -------------------------------------------------------------
__global__ void k_hist(const int* uid, int* counts) {
  int i = blockIdx.x * 256 + threadIdx.x;
  if (i < NROWS) atomicAdd(&counts[uid[i]], 1);
}

__global__ void k_scan(const int* counts, int* offs) {
  __shared__ int partial[256];
  int t = threadIdx.x;
  const int CH = (NUSERS + 255) / 256;  // 79
  int s = 0;
  for (int k = 0; k < CH; ++k) {
    int i = t * CH + k;
    if (i < NUSERS) s += counts[i];
  }
  partial[t] = s;
  __syncthreads();
  if (t == 0) {
    int run = 0;
    for (int k = 0; k < 256; ++k) { int v = partial[k]; partial[k] = run; run += v; }
  }
  __syncthreads();
  int run = partial[t];
  for (int k = 0; k < CH; ++k) {
    int i = t * CH + k;
    if (i < NUSERS) { offs[i] = run; run += counts[i]; }
  }
}

__global__ void k_scatter(const int* uid, const int* offs, int* cursor, int* rows) {
  int i = blockIdx.x * 256 + threadIdx.x;
  if (i < NROWS) {
    int u = uid[i];
    int p = offs[u] + atomicAdd(&cursor[u], 1);
    rows[p] = i;
  }
}

// ---- MFMA GEMM core --------------------------------------------------------
// Per wave: 16 output rows x 256 cols via 16 col-tiles of 16x16, K=256.
// A frag (mfma_f32_16x16x32_bf16): lane l -> row = l&15, k = (l>>4)*8 + e
// B frag: lane l -> col = l&15, k = (l>>4)*8 + e  (read from B^T [n][k] layout)
// C/D:    lane l -> col = l&15, row = (l>>4)*4 + reg   [measured: learn_hip m89]
template <int F32M>
__device__ __forceinline__ void load_afrags(const void* A, int row, int kq,
                                            bf16x8* afr, bf16x8* alo) {
  if (F32M) {
    const float* ap = (const float*)A + row * HDIM + kq;
#pragma unroll
    for (int ks = 0; ks < 8; ++ks) {
      bf16x8 h, l;
#pragma unroll
      for (int e = 0; e < 8; ++e) {
        float x = ap[ks * 32 + e];
        unsigned hb = bfr(x);
        h[e] = (short)(hb >> 16);
        float rem = x - __uint_as_float(hb);
        l[e] = (short)(bfr(rem) >> 16);
      }
      afr[ks] = h;
      alo[ks] = l;
    }
  } else {
    const short* ap = (const short*)A + row * HDIM + kq;
#pragma unroll
    for (int ks = 0; ks < 8; ++ks) afr[ks] = *(const bf16x8*)(ap + ks * 32);
  }
}

// acc = A @ (B_hi + B_lo) [+ A_lo @ B_hi if F32M], one 16x16 tile, K=256
template <int F32M>
__device__ __forceinline__ f32x4 tile_acc(const bf16x8* afr, const bf16x8* alo,
                                          const short* bh, const short* bl) {
  f32x4 acc = {0.f, 0.f, 0.f, 0.f};
#pragma unroll
  for (int ks = 0; ks < 8; ++ks) {
    bf16x8 bhf = *(const bf16x8*)(bh + ks * 32);
    acc = __builtin_amdgcn_mfma_f32_16x16x32_bf16(afr[ks], bhf, acc, 0, 0, 0);
    bf16x8 blf = *(const bf16x8*)(bl + ks * 32);
    acc = __builtin_amdgcn_mfma_f32_16x16x32_bf16(afr[ks], blf, acc, 0, 0, 0);
    if (F32M)
      acc = __builtin_amdgcn_mfma_f32_16x16x32_bf16(alo[ks], bhf, acc, 0, 0, 0);
  }
  return acc;
}

// sim[r] = rowsum((Ue @ M) .* S); S consumed elementwise (no split needed).
template <int F32M>
__global__ void __launch_bounds__(256) k_mm_sim_t(const void* Ue, const void* S,
    const __hip_bfloat16* pMT_hi, const __hip_bfloat16* pMT_lo,
    const int* flags, float* sim) {
  if (flags[2] != F32M) return;  // dual-instantiation dispatch on device flag
  const int lane = threadIdx.x & 63;
  const int rowBase = blockIdx.x * 64 + (threadIdx.x >> 6) * 16;
  const int r0 = lane & 15;
  const int kq = (lane >> 4) * 8;
  bf16x8 afr[8], alo[8];
  load_afrags<F32M>(Ue, rowBase + r0, kq, afr, alo);
  const int rgrp = rowBase + (lane >> 4) * 4;
  float psum0 = 0.f, psum1 = 0.f, psum2 = 0.f, psum3 = 0.f;
#pragma unroll 2
  for (int t = 0; t < 16; ++t) {
    const short* bh = (const short*)pMT_hi + (t * 16 + r0) * HDIM + kq;
    const short* bl = (const short*)pMT_lo + (t * 16 + r0) * HDIM + kq;
    f32x4 acc = tile_acc<F32M>(afr, alo, bh, bl);
    int col = t * 16 + r0;
    psum0 += acc[0] * ldx(S, (rgrp + 0) * HDIM + col, F32M);
    psum1 += acc[1] * ldx(S, (rgrp + 1) * HDIM + col, F32M);
    psum2 += acc[2] * ldx(S, (rgrp + 2) * HDIM + col, F32M);
    psum3 += acc[3] * ldx(S, (rgrp + 3) * HDIM + col, F32M);
  }
  // reduce across the 16 column-lanes of each group
#pragma unroll
  for (int off = 1; off < 16; off <<= 1) {
    psum0 += __shfl_xor(psum0, off);
    psum1 += __shfl_xor(psum1, off);
    psum2 += __shfl_xor(psum2, off);
    psum3 += __shfl_xor(psum3, off);
  }
  if (r0 == 0) {
    sim[rgrp + 0] = psum0;
    sim[rgrp + 1] = psum1;
    sim[rgrp + 2] = psum2;
    sim[rgrp + 3] = psum3;
  }
}

// Y[u] = wsum[u] @ W1b^T   (wsum bf16 exact, B split hi/lo)
__global__ void __launch_bounds__(256) k_mm_y2(const __hip_bfloat16* wsum,
    const __hip_bfloat16* pBT_hi, const __hip_bfloat16* pBT_lo, float* Y) {
  const int lane = threadIdx.x & 63;
  const int rowBase = blockIdx.x * 64 + (threadIdx.x >> 6) * 16;
  if (rowBase >= NUSERS) return;
  const int r0 = lane & 15;
  const int kq = (lane >> 4) * 8;
  bf16x8 afr[8], alo[8];
  load_afrags<0>((const void*)wsum, rowBase + r0, kq, afr, alo);
  const int rgrp = rowBase + (lane >> 4) * 4;
#pragma unroll 2
  for (int t = 0; t < 16; ++t) {
    const short* bh = (const short*)pBT_hi + (t * 16 + r0) * HDIM + kq;
    const short* bl = (const short*)pBT_lo + (t * 16 + r0) * HDIM + kq;
    f32x4 acc = tile_acc<0>(afr, alo, bh, bl);
    int col = t * 16 + r0;
#pragma unroll
    for (int g = 0; g < 4; ++g) Y[(rgrp + g) * HDIM + col] = acc[g];
  }
}

// out[r] = relu(Ue[r] @ P + Y[uid[r]] + b1), dtype per flag
template <int F32M>
__global__ void __launch_bounds__(256) k_mm_out_t(const void* Ue,
    const __hip_bfloat16* pPT_hi, const __hip_bfloat16* pPT_lo,
    const int* uid, const float* Y, const void* b1, const int* flags, void* outv) {
  if (flags[2] != F32M) return;
  const int lane = threadIdx.x & 63;
  const int rowBase = blockIdx.x * 64 + (threadIdx.x >> 6) * 16;
  const int r0 = lane & 15;
  const int kq = (lane >> 4) * 8;
  bf16x8 afr[8], alo[8];
  load_afrags<F32M>(Ue, rowBase + r0, kq, afr, alo);
  const int rgrp = rowBase + (lane >> 4) * 4;
  int ug[4];
#pragma unroll
  for (int g = 0; g < 4; ++g) ug[g] = uid[rgrp + g];
#pragma unroll 2
  for (int t = 0; t < 16; ++t) {
    const short* bh = (const short*)pPT_hi + (t * 16 + r0) * HDIM + kq;
    const short* bl = (const short*)pPT_lo + (t * 16 + r0) * HDIM + kq;
    f32x4 acc = tile_acc<F32M>(afr, alo, bh, bl);
    int col = t * 16 + r0;
    float bias = ldx(b1, col, F32M);
#pragma unroll
    for (int g = 0; g < 4; ++g) {
      float v = acc[g] + Y[ug[g] * HDIM + col] + bias;
      if (!(v > 0.0f)) v = 0.0f;
      if (F32M)
        ((float*)outv)[(rgrp + g) * HDIM + col] = v;
      else
        ((__hip_bfloat16*)outv)[(rgrp + g) * HDIM + col] = __float2bfloat16(v);
    }
  }
}

// ---- segment softmax -------------------------------------------------------
__global__ void k_segmax(const float* sim, const int* uid, int* segmaxB) {
  int i = blockIdx.x * 256 + threadIdx.x;
  if (i < NROWS) {
    float v = sim[i];
    int u = uid[i];
    if (v >= 0.0f)
      atomicMax(&segmaxB[u], __float_as_int(v));
    else
      atomicMin((unsigned int*)&segmaxB[u], __float_as_uint(v));
  }
}

__global__ void k_expdenom(const float* sim, const int* uid, const int* segmaxB,
                           float* e, float* denom) {
  int i = blockIdx.x * 256 + threadIdx.x;
  if (i < NROWS) {
    int u = uid[i];
    float m = __int_as_float(segmaxB[u]);
    float ev = __expf(sim[i] - m);
    e[i] = ev;
    atomicAdd(&denom[u], ev);
  }
}

// ---- weighted segment sum: wsum[u] = sum_i w_i * Ue[i]  (bf16 out) ---------
__global__ void k_wsum(const void* Ue, const int* offs, const int* counts,
                       const float* e, const float* denom, const int* rows,
                       const int* flags, __hip_bfloat16* wsum) {
  int u = blockIdx.x * 4 + (threadIdx.x >> 6);
  int lane = threadIdx.x & 63;
  if (u >= NUSERS) return;
  int off = offs[u], cnt = counts[u];
  int f32m = flags[2];
  float rd = 0.0f;
  if (cnt > 0) rd = 1.0f / denom[u];
  float a0 = 0.0f, a1 = 0.0f, a2 = 0.0f, a3 = 0.0f;
  for (int j = 0; j < cnt; ++j) {
    int i = rows[off + j];
    float w = e[i] * rd;
    int base = i * HDIM + lane * 4;
    a0 += w * ldx(Ue, base + 0, f32m);
    a1 += w * ldx(Ue, base + 1, f32m);
    a2 += w * ldx(Ue, base + 2, f32m);
    a3 += w * ldx(Ue, base + 3, f32m);
  }
  __hip_bfloat16* q = &wsum[u * HDIM + lane * 4];
  q[0] = __float2bfloat16(a0);
  q[1] = __float2bfloat16(a1);
  q[2] = __float2bfloat16(a2);
  q[3] = __float2bfloat16(a3);
}

extern "C" void kernel_launch(void* const* d_in, const int* in_sizes, int n_in,
                              void* d_out, int out_size, void* d_ws, size_t ws_size,
                              hipStream_t stream) {
  (void)in_sizes; (void)n_in; (void)out_size; (void)ws_size;
  const void* S  = d_in[0];
  const void* Ue = d_in[1];
  const int* uid_raw = (const int*)d_in[2];
  const void* Wq = d_in[3];
  const void* Wk = d_in[4];
  const void* Wv = d_in[5];
  const void* W1 = d_in[6];
  const void* b1 = d_in[7];

  char* w = (char*)d_ws;
  __hip_bfloat16* pMT_hi = (__hip_bfloat16*)(w + 0);        // 128 KB
  __hip_bfloat16* pMT_lo = (__hip_bfloat16*)(w + 131072);   // 128 KB
  __hip_bfloat16* pPT_hi = (__hip_bfloat16*)(w + 262144);   // 128 KB
  __hip_bfloat16* pPT_lo = (__hip_bfloat16*)(w + 393216);   // 128 KB
  __hip_bfloat16* pBT_hi = (__hip_bfloat16*)(w + 524288);   // 128 KB
  __hip_bfloat16* pBT_lo = (__hip_bfloat16*)(w + 655360);   // 128 KB
  float* sim    = (float*)(w + 786432);    // N*4
  float* e      = (float*)(w + 1586432);   // N*4
  int* segmaxB  = (int*)  (w + 2386432);   // U*4
  float* denom  = (float*)(w + 2466432);   // U*4
  int* counts   = (int*)  (w + 2546432);   // U*4
  int* cursor   = (int*)  (w + 2626432);   // U*4
  int* offs     = (int*)  (w + 2706432);   // U*4
  int* rows     = (int*)  (w + 2786432);   // N*4
  int* uid      = (int*)  (w + 3586432);   // N*4
  int* flags    = (int*)  (w + 4386432);   // 256 B
  __hip_bfloat16* wsum = (__hip_bfloat16*)(w + 4386688);  // U*H*2 = 10.24 MB
  float* Y      = (float*)(w + 14626688);  // U*H*4 = 20.48 MB -> ends ~35.1 MB

  k_init<<<(NUSERS + 255) / 256, 256, 0, stream>>>(counts, cursor, denom, segmaxB, flags);
  k_dtype<<<4, 256, 0, stream>>>((const unsigned int*)S, flags);
  k_flagfin<<<1, 64, 0, stream>>>(flags);
  k_detect<<<4, 256, 0, stream>>>(uid_raw, flags);
  k_cvt<<<(NROWS + 255) / 256, 256, 0, stream>>>(uid_raw, flags, uid);
  k_pack<<<HDIM, HDIM, 0, stream>>>(Wq, Wk, Wv, W1, flags,
                                    pMT_hi, pMT_lo, pPT_hi, pPT_lo, pBT_hi, pBT_lo);
  k_hist<<<(NROWS + 255) / 256, 256, 0, stream>>>(uid, counts);
  k_scan<<<1, 256, 0, stream>>>(counts, offs);
  k_scatter<<<(NROWS + 255) / 256, 256, 0, stream>>>(uid, offs, cursor, rows);
  // sim = rowsum((Ue @ M) .* S)   — MFMA, dual-dtype via device-flag dispatch
  k_mm_sim_t<0><<<NROWS / 64, 256, 0, stream>>>(Ue, S, pMT_hi, pMT_lo, flags, sim);
  k_mm_sim_t<1><<<NROWS / 64, 256, 0, stream>>>(Ue, S, pMT_hi, pMT_lo, flags, sim);
  k_segmax<<<(NROWS + 255) / 256, 256, 0, stream>>>(sim, uid, segmaxB);
  k_expdenom<<<(NROWS + 255) / 256, 256, 0, stream>>>(sim, uid, segmaxB, e, denom);
  k_wsum<<<(NUSERS + 3) / 4, 256, 0, stream>>>(Ue, offs, counts, e, denom, rows, flags, wsum);
  // Y = wsum @ W1b^T — MFMA
  k_mm_y2<<<(NUSERS / 16 + 3) / 4, 256, 0, stream>>>(wsum, pBT_hi, pBT_lo, Y);
  // out = relu(Ue @ P + Y[uid] + b1) — MFMA
  k_mm_out_t<0><<<NROWS / 64, 256, 0, stream>>>(Ue, pPT_hi, pPT_lo, uid, Y, b1, flags, d_out);
  k_mm_out_t<1><<<NROWS / 64, 256, 0, stream>>>(Ue, pPT_hi, pPT_lo, uid, Y, b1, flags, d_out);
}